// Round 11
// baseline (108.439 us; speedup 1.0000x reference)
//
#include <hip/hip_runtime.h>

#define LSEQ 512
#define NB 64
#define NCHUNK 71  // 71*16 = 1136 >= 512 + 7*80 + 63 = 1135 steps

// lanes 1..63 <- x[lane-1]; lane 0 <- old[0] (wave_shr:1, bound_ctrl=0 ->
// invalid lane takes OLD). Fuses the lane-0 injection select into the DPP.
__device__ __forceinline__ float dpp_shr1(float old, float x) {
  return __int_as_float(__builtin_amdgcn_update_dpp(
      __float_as_int(old), __float_as_int(x), 0x138, 0xF, 0xF, false));
}
// lane l <- lane l+1 (wave_shl:1) — rotates injection registers.
__device__ __forceinline__ float dpp_shl1(float x) {
  return __int_as_float(__builtin_amdgcn_update_dpp(
      0, __float_as_int(x), 0x130, 0xF, 0xF, false));
}

// Cell state is a PAIR (dm, e) representing v = dm - log2(e) (scaled domain
// R' = C1*R, inputs pre-scaled by sqrt(C1)). Update with M = min3(dm_i):
//   t_i = exp2(M - dm_i) * e_i   (args <= 0 -> t_i <= e_i, no overflow)
//   e_new = t0 + t1 + tP ; dm_new = diff^2 + M
// Mathematically exact softmin (log deferred to the very end); exp2 args come
// off the fast dm-chain (dpp->min3->fma ~20cy/step), so trans LATENCY (~68cy,
// the R9/R10 wall) is a pipeline offset, not a per-step serial cost.
template <bool FULL>
__device__ __forceinline__ void chunk16(int cbase, const float* tgp,
                                        const float2* ring2P, float2* ring2W,
                                        float p, bool is_wr, int lane,
                                        float& vd, float& ve, float& r0d,
                                        float& r0e, float& tcur) {
  // renormalize vprev pair (exact; ve in [1, 2*3^16] stays far from overflow)
  const int eb = __float_as_int(ve);
  const int E = (eb >> 23) - 127;
  ve = __int_as_float((eb & 0x007FFFFF) | 0x3F800000);
  vd -= (float)E;

  // injection registers: lane k (mod 16) holds step-k values for lane 0
  float tinj = tgp[(cbase + (lane & 15)) & 511];
  const float2 rj = ring2P[(cbase + 1 + (lane & 15)) & 127];
  float rdinj = rj.x, reinj = rj.y;

  float2 vv[16];
#pragma unroll
  for (int u = 0; u < 16; ++u) {
    tcur = dpp_shr1(tinj, tcur);            // target'[j-1]
    const float r1d = dpp_shr1(rdinj, vd);  // R'[i-1][j] pair
    const float r1e = dpp_shr1(reinj, ve);
    if (u < 15) {  // rotate injections for next step
      tinj = dpp_shl1(tinj);
      rdinj = dpp_shl1(rdinj);
      reinj = dpp_shl1(reinj);
    }
    const float diff = p - tcur;
    const float M = fminf(fminf(r0d, r1d), vd);  // min3 over dm's
    const float t0 = __builtin_amdgcn_exp2f(M - r0d) * r0e;
    const float t1 = __builtin_amdgcn_exp2f(M - r1d) * r1e;
    const float tP = __builtin_amdgcn_exp2f(M - vd) * ve;
    const float eN = (t0 + t1) + tP;
    const float dN = __builtin_fmaf(diff, diff, M);
    vv[u] = make_float2(dN, eN);
    if (FULL) {
      vd = dN;
      ve = eN;
    } else {
      const int j = cbase + 1 + u - lane;
      const bool act = ((unsigned)(j - 1)) < (unsigned)LSEQ;
      vd = act ? dN : vd;  // inactive lanes keep (INF, 1); garbage (incl.
      ve = act ? eN : ve;  // NaN from all-INF preds) is discarded here
    }
    r0d = r1d;
    r0e = r1e;
  }

  if (is_wr) {  // lane 63 bursts its 16 (dm,e) pairs into the ring
    const int wb = (cbase - 62) & 127;
#pragma unroll
    for (int k = 0; k < 16; ++k) ring2W[(wb + k) & 127] = vv[k];
  }
}

// Soft-DTW banded wavefront, one block per batch, 8 waves x 64 lanes.
// Lane l of wave w owns row i = 64w+l+1, column j = s - 80w - l at step s.
// In-wave neighbors via DPP; cross-wave via LDS float2 ring + barrier every
// 16 steps. Ring col J read by wave w at step J+80w; written by wave w-1 at
// step J+80w-17 (gap 17 > 16 -> >=1 barrier between write-burst and read).
// Out-of-range garbage writes alias slots whose legit write precedes the
// consumer's read (same timing proof as R9/R10).
__global__ __launch_bounds__(512) void dtw_band(
    const float* __restrict__ pred, const float* __restrict__ target,
    float* __restrict__ part) {
  const int b = blockIdx.x;
  const int tid = threadIdx.x;
  const int w = tid >> 6;
  const int lane = tid & 63;
  const bool is_wr = (lane == 63) && (w < 7);

  __shared__ float tg[LSEQ];
  __shared__ float2 rings2[8][128];  // row w: band-bottom row of wave w; 7: INF

  const float SC = 3.79828146f;  // sqrt(C1), C1 = (1/g)*log2(e), g = 0.1
  const float p = pred[b * LSEQ + tid] * SC;
  tg[tid] = target[b * LSEQ + tid] * SC;
  // init all ring pairs to (INF, 1): even float = INF, odd = 1
  float* rf = (float*)rings2;
  rf[tid] = (tid & 1) ? 1.0f : INFINITY;
  rf[tid + 512] = (tid & 1) ? 1.0f : INFINITY;
  rf[tid + 1024] = (tid & 1) ? 1.0f : INFINITY;
  rf[tid + 1536] = (tid & 1) ? 1.0f : INFINITY;

  const int lag = w * 80;
  const int cw0 = 5 * w;  // wave-active chunks: [cw0, cw0+35]
  const float2* __restrict__ ring2P = rings2[w == 0 ? 7 : w - 1];
  float2* __restrict__ ring2W = rings2[w];

  float vd = INFINITY, ve = 1.0f;           // vprev pair: R'[i][j-1]
  float r0d = (tid == 0) ? 0.0f : INFINITY; // R'[i-1][j-1]; seed R'[0][0]=0
  float r0e = 1.0f;
  float tcur = 0.0f;

  for (int c = 0; c < NCHUNK; ++c) {
    __syncthreads();  // top of chunk c (also orders init writes at c=0)
    if (c < cw0 || c > cw0 + 35) continue;  // wave-uniform
    const int cbase = 16 * c - lag;
    if (c >= cw0 + 4 && c <= cw0 + 31)
      chunk16<true>(cbase, tg, ring2P, ring2W, p, is_wr, lane, vd, ve, r0d,
                    r0e, tcur);
    else
      chunk16<false>(cbase, tg, ring2P, ring2W, p, is_wr, lane, vd, ve, r0d,
                     r0e, tcur);
  }

  if (tid == LSEQ - 1)  // v = dm - log2(e), then unscale by 1/C1 = g*ln2
    part[b] = (vd - __builtin_amdgcn_logf(ve)) * 0.069314718f;
}

__global__ void dtw_reduce(const float* __restrict__ part,
                           float* __restrict__ out) {
  float v = part[threadIdx.x];
#pragma unroll
  for (int o = 32; o > 0; o >>= 1) v += __shfl_down(v, o);
  if (threadIdx.x == 0) out[0] = v * (1.0f / NB);
}

extern "C" void kernel_launch(void* const* d_in, const int* in_sizes, int n_in,
                              void* d_out, int out_size, void* d_ws,
                              size_t ws_size, hipStream_t stream) {
  const float* pred = (const float*)d_in[0];
  const float* target = (const float*)d_in[1];
  float* part = (float*)d_ws;

  dtw_band<<<NB, LSEQ, 0, stream>>>(pred, target, part);
  dtw_reduce<<<1, 64, 0, stream>>>(part, (float*)d_out);
}

// Round 13
// 90.285 us; speedup vs baseline: 1.2011x; 1.2011x over previous
//
#include <hip/hip_runtime.h>

#define LSEQ 512
#define NB 64
#define NCHUNK 51  // 16*51 = 816 >= 512 + 3*80 + 63 = 815 steps

// lanes 1..63 <- x[lane-1]; lane 0 <- old[0] (wave_shr:1, bound_ctrl=0 ->
// invalid lane takes OLD). Proven idiom from R11 (passed).
__device__ __forceinline__ float dpp_shr1(float old, float x) {
  return __int_as_float(__builtin_amdgcn_update_dpp(
      __float_as_int(old), __float_as_int(x), 0x138, 0xF, 0xF, false));
}
// lane l <- lane l+1 (wave_shl:1) — rotates injection registers (R10/R11).
__device__ __forceinline__ float dpp_shl1(float x) {
  return __int_as_float(__builtin_amdgcn_update_dpp(
      0, __float_as_int(x), 0x130, 0xF, 0xF, false));
}

// (d,e) pair encodes v = d - log2(e); exact softmin, log deferred to the end.
// Renorm once per chunk keeps e in [1, ~9^16]; e >= e_argmin >= 1 always.
__device__ __forceinline__ void renorm(float& d, float& e) {
  const int eb = __float_as_int(e);
  const int E = (eb >> 23) - 127;
  e = __int_as_float((eb & 0x007FFFFF) | 0x3F800000);
  d -= (float)E;
}

// One 16-step chunk, TWO rows per lane (i0 = 128w+2l+1, i1 = i0+1), both at
// column j = cbase+1+u-lane. Cell0's up/diag come from lane l-1 (DPP / lane-0
// ring injection); cell1's preds are all lane-local: diag = v0_old, up = fresh
// cell0 result, left = v1_old -> zero movement ops for the second row.
template <bool FULL>
__device__ __forceinline__ void chunk16(
    int cbase, const float* tg, const float2* ring2P, float2* ring2W, float p0,
    float p1, bool is_wr, int lane, float& v0d, float& v0e, float& v1d,
    float& v1e, float& r0d, float& r0e, float& tcur) {
  renorm(v0d, v0e);
  renorm(v1d, v1e);

  // injection registers: lane k (mod 16) holds step-k data for lane 0
  float tinj = tg[(cbase + (lane & 15)) & 511];
  const float2 rj = ring2P[(cbase + 1 + (lane & 15)) & 127];
  float rdinj = rj.x, reinj = rj.y;

  float2 vv[16];
#pragma unroll
  for (int u = 0; u < 16; ++u) {
    tcur = dpp_shr1(tinj, tcur);            // target'[j-1] (shared by rows)
    const float r1d = dpp_shr1(rdinj, v1d); // R'[i0-1][j] pair
    const float r1e = dpp_shr1(reinj, v1e);
    if (u < 15) {  // rotate injections for next step
      tinj = dpp_shl1(tinj);
      rdinj = dpp_shl1(rdinj);
      reinj = dpp_shl1(reinj);
    }
    // cell0 (row i0): diag (r0d,r0e), up (r1d,r1e), left (v0d,v0e)
    const float diff0 = p0 - tcur;
    const float M0 = fminf(fminf(r0d, r1d), v0d);
    const float e0 = (__builtin_amdgcn_exp2f(M0 - r0d) * r0e +
                      __builtin_amdgcn_exp2f(M0 - r1d) * r1e) +
                     __builtin_amdgcn_exp2f(M0 - v0d) * v0e;
    const float d0 = __builtin_fmaf(diff0, diff0, M0);
    // cell1 (row i1): diag (v0d,v0e)_old, up (d0,e0), left (v1d,v1e)
    const float diff1 = p1 - tcur;
    const float M1 = fminf(fminf(v0d, d0), v1d);
    const float e1 = (__builtin_amdgcn_exp2f(M1 - v0d) * v0e +
                      __builtin_amdgcn_exp2f(M1 - d0) * e0) +
                     __builtin_amdgcn_exp2f(M1 - v1d) * v1e;
    const float d1 = __builtin_fmaf(diff1, diff1, M1);
    vv[u] = make_float2(d1, e1);
    if (FULL) {
      v0d = d0; v0e = e0; v1d = d1; v1e = e1;
    } else {
      const int j = cbase + 1 + u - lane;
      const bool act = ((unsigned)(j - 1)) < (unsigned)LSEQ;
      v0d = act ? d0 : v0d; v0e = act ? e0 : v0e;  // inactive lanes keep
      v1d = act ? d1 : v1d; v1e = act ? e1 : v1e;  // (INF,1); NaN discarded
    }
    r0d = r1d;
    r0e = r1e;
  }

  if (is_wr) {  // lane 63 publishes row 128(w+1) = its i1
    const int j0 = cbase - 62;  // lane 63's first column this chunk
#pragma unroll
    for (int k = 0; k < 16; ++k) {
      // guard: only real columns enter the ring (no garbage/NaN ever written;
      // unwritten slots keep their (INF,1) init until the legit write)
      if (FULL || (((unsigned)(j0 + k - 1)) < (unsigned)LSEQ))
        ring2W[(j0 + k) & 127] = vv[k];
    }
  }
}

// Soft-DTW banded wavefront, one block per batch, 4 waves x 64 lanes x 2 rows.
// Lane l of wave w owns rows 128w+2l+1, +2; column j = s - 80w - l at step s.
// Ring (lag=80, single-barrier proof as R9-R11): entry col J read by wave w at
// top of chunk c (J in [16c-80w+1, +16]) was written by wave w-1 at step
// J+80w-17 in [16c-16, 16c-1] = its chunk c-1, burst before the top-of-c
// barrier. Barriers lockstep the chunk index, so during wave w's chunk-c body
// wave w-1 writes only cols [16c-80w+18, +33] — disjoint from the read window.
__global__ __launch_bounds__(256) void dtw_band(
    const float* __restrict__ pred, const float* __restrict__ target,
    float* __restrict__ part) {
  const int b = blockIdx.x;
  const int tid = threadIdx.x;  // 0..255
  const int w = tid >> 6;
  const int lane = tid & 63;
  const bool is_wr = (lane == 63) && (w < 3);

  __shared__ float tg[LSEQ];
  __shared__ float2 rings2[4][128];  // rows 0..2: interfaces; row 3: INF dummy

  const float SC = 3.79828146f;  // sqrt(C1), C1 = (1/g)*log2(e), g = 0.1
  const float2 pp = ((const float2*)(pred + b * LSEQ))[tid];
  const float p0 = pp.x * SC, p1 = pp.y * SC;  // rows 2*tid+1, 2*tid+2
  const float2 tt = ((const float2*)(target + b * LSEQ))[tid];
  ((float2*)tg)[tid] = make_float2(tt.x * SC, tt.y * SC);
  ((float2*)rings2)[tid] = make_float2(INFINITY, 1.0f);
  ((float2*)rings2)[tid + 256] = make_float2(INFINITY, 1.0f);

  const int lag = w * 80;
  const int cw0 = 5 * w;  // wave-active chunks: [cw0, cw0+35]
  const float2* __restrict__ ring2P = rings2[w == 0 ? 3 : w - 1];
  float2* __restrict__ ring2W = rings2[w];

  float v0d = INFINITY, v0e = 1.0f;          // R'[i0][j-1]
  float v1d = INFINITY, v1e = 1.0f;          // R'[i1][j-1]
  float r0d = (tid == 0) ? 0.0f : INFINITY;  // R'[i0-1][j-1]; seed R'[0][0]
  float r0e = 1.0f;
  float tcur = 0.0f;

  for (int c = 0; c < NCHUNK; ++c) {
    __syncthreads();  // top of chunk c (also orders init writes at c=0)
    if (c < cw0 || c > cw0 + 35) continue;  // wave-uniform
    const int cbase = 16 * c - lag;
    if (c >= cw0 + 4 && c <= cw0 + 31)
      chunk16<true>(cbase, tg, ring2P, ring2W, p0, p1, is_wr, lane, v0d, v0e,
                    v1d, v1e, r0d, r0e, tcur);
    else
      chunk16<false>(cbase, tg, ring2P, ring2W, p0, p1, is_wr, lane, v0d, v0e,
                     v1d, v1e, r0d, r0e, tcur);
  }

  if (tid == 255)  // row 512 = wave 3 lane 63 i1; unscale by 1/C1 = g*ln2
    part[b] = (v1d - __builtin_amdgcn_logf(v1e)) * 0.069314718f;
}

__global__ void dtw_reduce(const float* __restrict__ part,
                           float* __restrict__ out) {
  float v = part[threadIdx.x];
#pragma unroll
  for (int o = 32; o > 0; o >>= 1) v += __shfl_down(v, o);
  if (threadIdx.x == 0) out[0] = v * (1.0f / NB);
}

extern "C" void kernel_launch(void* const* d_in, const int* in_sizes, int n_in,
                              void* d_out, int out_size, void* d_ws,
                              size_t ws_size, hipStream_t stream) {
  const float* pred = (const float*)d_in[0];
  const float* target = (const float*)d_in[1];
  float* part = (float*)d_ws;

  dtw_band<<<NB, 256, 0, stream>>>(pred, target, part);
  dtw_reduce<<<1, 64, 0, stream>>>(part, (float*)d_out);
}